// Round 1
// baseline (649.819 us; speedup 1.0000x reference)
//
#include <hip/hip_runtime.h>

#define IMG_H 512
#define IMG_W 512
#define TILE_COLS 256              // output cols per block
#define HALO 5
#define VCOLS (TILE_COLS + 2*HALO) // 266 columns computed by vertical stage
#define RCHUNK 8                   // output rows per chunk
#define CHUNKS 16                  // 128 rows per block
#define NTHREADS 320               // 5 waves
#define VSTRIDE 268                // float stride, multiple of 4 (16B aligned rows)

// Gaussian(sigma=1.5), 11 taps, normalized (sum = 1 - 3e-7)
static constexpr float GW[11] = {
    0.00102838f, 0.00759876f, 0.03600077f, 0.10936053f, 0.21300556f,
    0.26601170f,
    0.21300556f, 0.10936053f, 0.03600077f, 0.00759876f, 0.00102838f
};

__device__ __forceinline__ void hconv4(const float* __restrict__ p, float out[4]) {
    float f[16];
#pragma unroll
    for (int v = 0; v < 4; ++v) {
        const float4 t = *(const float4*)(p + 4*v);   // ds_read_b128, 16B aligned
        f[4*v+0] = t.x; f[4*v+1] = t.y; f[4*v+2] = t.z; f[4*v+3] = t.w;
    }
#pragma unroll
    for (int o = 0; o < 4; ++o) {
        float s = 0.f;
#pragma unroll
        for (int t = 0; t < 11; ++t) s = fmaf(GW[t], f[o+t], s);
        out[o] = s;
    }
}

__global__ __launch_bounds__(NTHREADS)
void ssim_fused(const float* __restrict__ den, const float* __restrict__ cln,
                double* __restrict__ gacc) {
    __shared__ __align__(16) float vbuf[5][RCHUNK][VSTRIDE]; // 42,880 B
    __shared__ float red[NTHREADS/64];

    const int tid = threadIdx.x;
    const int b  = blockIdx.x;
    const int cs = b & 1;           // col strip (2)
    const int rs = (b >> 1) & 3;    // row strip (4)
    const int plane = b >> 3;       // 96 planes (B*C)

    const int c0 = cs * TILE_COLS;
    const int y0 = rs * (RCHUNK * CHUNKS);
    const int gc = c0 - HALO + tid;                     // global col this thread owns
    const bool colok = (tid < VCOLS) && (gc >= 0) && (gc < IMG_W);
    const size_t pbase = (size_t)plane * (IMG_H * IMG_W);

    // register ring: rows y0+8k-5 .. y0+8k+12 live in rx/ry[0..17]
    float rx[18], ry[18];
#pragma unroll
    for (int i = 0; i < 10; ++i) {
        int gr = y0 - HALO + i;
        float x = 0.f, y = 0.f;
        if (colok && gr >= 0 && gr < IMG_H) {
            size_t idx = pbase + (size_t)gr * IMG_W + gc;
            x = den[idx]; y = cln[idx];
        }
        rx[i] = fminf(fmaxf(x, 0.f), 1.f);
        ry[i] = fminf(fmaxf(y, 0.f), 1.f);
    }

    float ssim_acc = 0.f;

    for (int k = 0; k < CHUNKS; ++k) {
        // ---- load 8 new rows (y0+8k+5 .. y0+8k+12) ----
#pragma unroll
        for (int i = 0; i < RCHUNK; ++i) {
            int gr = y0 + k * RCHUNK + HALO + i;
            float x = 0.f, y = 0.f;
            if (colok && gr < IMG_H) {
                size_t idx = pbase + (size_t)gr * IMG_W + gc;
                x = den[idx]; y = cln[idx];
            }
            rx[10+i] = fminf(fmaxf(x, 0.f), 1.f);
            ry[10+i] = fminf(fmaxf(y, 0.f), 1.f);
        }
        // ---- vertical 11-tap conv of {x, y, x2, y2, xy} for 8 output rows ----
        float a0[RCHUNK], a1[RCHUNK], a2[RCHUNK], a3[RCHUNK], a4[RCHUNK];
#pragma unroll
        for (int r = 0; r < RCHUNK; ++r) { a0[r]=a1[r]=a2[r]=a3[r]=a4[r]=0.f; }
#pragma unroll
        for (int i = 0; i < 18; ++i) {
            float x = rx[i], y = ry[i];
            float xx = x*x, yy = y*y, xy = x*y;
#pragma unroll
            for (int r = 0; r < RCHUNK; ++r) {
                if (i - r >= 0 && i - r <= 10) {
                    const float w = GW[i - r];
                    a0[r] = fmaf(w, x,  a0[r]);
                    a1[r] = fmaf(w, y,  a1[r]);
                    a2[r] = fmaf(w, xx, a2[r]);
                    a3[r] = fmaf(w, yy, a3[r]);
                    a4[r] = fmaf(w, xy, a4[r]);
                }
            }
        }
        if (tid < VCOLS) {
#pragma unroll
            for (int r = 0; r < RCHUNK; ++r) {
                vbuf[0][r][tid] = a0[r];
                vbuf[1][r][tid] = a1[r];
                vbuf[2][r][tid] = a2[r];
                vbuf[3][r][tid] = a3[r];
                vbuf[4][r][tid] = a4[r];
            }
        }
        __syncthreads();

        // ---- horizontal 11-tap conv + SSIM, 4 consecutive cols per thread-group ----
        for (int g = tid; g < (TILE_COLS/4) * RCHUNK; g += NTHREADS) {
            const int row = g >> 6;           // TILE_COLS/4 == 64
            const int j4  = (g & 63) << 2;    // 16B-aligned start col in vbuf
            float bx[4], by[4], bxx[4], byy[4], bxy[4];
            hconv4(&vbuf[0][row][j4], bx);
            hconv4(&vbuf[1][row][j4], by);
            hconv4(&vbuf[2][row][j4], bxx);
            hconv4(&vbuf[3][row][j4], byy);
            hconv4(&vbuf[4][row][j4], bxy);
#pragma unroll
            for (int o = 0; o < 4; ++o) {
                const float C1 = 1e-4f, C2 = 9e-4f;
                float mu1 = bx[o], mu2 = by[o];
                float mu1s = mu1*mu1, mu2s = mu2*mu2, mu12 = mu1*mu2;
                float s1  = bxx[o] - mu1s;
                float s2  = byy[o] - mu2s;
                float s12 = bxy[o] - mu12;
                float num = (2.f*mu12 + C1) * (2.f*s12 + C2);
                float dnm = (mu1s + mu2s + C1) * (s1 + s2 + C2);
                ssim_acc += num / dnm;
            }
        }
        __syncthreads();   // protect vbuf before next chunk overwrites

        // ---- slide ring by 8 rows ----
#pragma unroll
        for (int i = 0; i < 10; ++i) { rx[i] = rx[i+8]; ry[i] = ry[i+8]; }
    }

    // ---- block reduction, one f64 atomic per block ----
#pragma unroll
    for (int off = 32; off > 0; off >>= 1)
        ssim_acc += __shfl_down(ssim_acc, off, 64);
    if ((tid & 63) == 0) red[tid >> 6] = ssim_acc;
    __syncthreads();
    if (tid == 0) {
        float s = 0.f;
#pragma unroll
        for (int w = 0; w < NTHREADS/64; ++w) s += red[w];
        atomicAdd(gacc, (double)s);
    }
}

__global__ void ssim_finalize(const double* __restrict__ gacc, float* __restrict__ out,
                              double inv_n) {
    out[0] = 1.0f - (float)(gacc[0] * inv_n);
}

extern "C" void kernel_launch(void* const* d_in, const int* in_sizes, int n_in,
                              void* d_out, int out_size, void* d_ws, size_t ws_size,
                              hipStream_t stream) {
    const float* den = (const float*)d_in[0];
    const float* cln = (const float*)d_in[1];
    float* out = (float*)d_out;
    double* acc = (double*)d_ws;

    hipMemsetAsync(acc, 0, sizeof(double), stream);

    const int n = in_sizes[0];                 // 32*3*512*512
    const int planes = n / (IMG_H * IMG_W);    // 96
    dim3 grid(planes * 2 * 4);                 // 2 col strips x 4 row strips
    ssim_fused<<<grid, NTHREADS, 0, stream>>>(den, cln, acc);
    ssim_finalize<<<1, 1, 0, stream>>>(acc, out, 1.0 / (double)n);
}

// Round 2
// 453.684 us; speedup vs baseline: 1.4323x; 1.4323x over previous
//
#include <hip/hip_runtime.h>

#define IMG_H 512
#define IMG_W 512
#define TILE_COLS 256               // output cols per block
#define TILE_ROWS 8                 // output rows per block
#define HALO 5
#define VCOLS (TILE_COLS + 2*HALO)  // 266 columns produced by vertical stage
#define NTHREADS 256                // 4 waves
#define VSTRIDE 268                 // float stride, multiple of 4 (16B-aligned rows)
#define NROWS_IN (TILE_ROWS + 2*HALO)  // 18 input rows

// Gaussian(sigma=1.5), 11 taps, normalized
static constexpr float GW[11] = {
    0.00102838f, 0.00759876f, 0.03600077f, 0.10936053f, 0.21300556f,
    0.26601170f,
    0.21300556f, 0.10936053f, 0.03600077f, 0.00759876f, 0.00102838f
};

__device__ __forceinline__ void hconv4(const float* __restrict__ p, float out[4]) {
    float f[16];
#pragma unroll
    for (int v = 0; v < 4; ++v) {
        const float4 t = *(const float4*)(p + 4*v);   // ds_read_b128, 16B aligned
        f[4*v+0] = t.x; f[4*v+1] = t.y; f[4*v+2] = t.z; f[4*v+3] = t.w;
    }
#pragma unroll
    for (int o = 0; o < 4; ++o) {
        float s = 0.f;
#pragma unroll
        for (int t = 0; t < 11; ++t) s = fmaf(GW[t], f[o+t], s);
        out[o] = s;
    }
}

// Vertical 11-tap conv of {x,y,x^2,y^2,xy} for one column v (0..VCOLS-1),
// 8 output rows, results written to vbuf[q][r][v].
__device__ __forceinline__ void vertical_col(
    int v, int c0, int y0, size_t pbase,
    const float* __restrict__ den, const float* __restrict__ cln,
    float (*vbuf)[TILE_ROWS][VSTRIDE]) {
    const int gc = c0 - HALO + v;
    const bool colok = (gc >= 0) && (gc < IMG_W);

    float xv[NROWS_IN], yv[NROWS_IN];
#pragma unroll
    for (int i = 0; i < NROWS_IN; ++i) {
        const int gr = y0 - HALO + i;
        const bool ok = colok && ((unsigned)gr < (unsigned)IMG_H);
        float x = 0.f, y = 0.f;
        if (ok) {
            const size_t idx = pbase + (size_t)gr * IMG_W + gc;
            x = den[idx]; y = cln[idx];
        }
        xv[i] = fminf(fmaxf(x, 0.f), 1.f);
        yv[i] = fminf(fmaxf(y, 0.f), 1.f);
    }

    float a0[TILE_ROWS], a1[TILE_ROWS], a2[TILE_ROWS], a3[TILE_ROWS], a4[TILE_ROWS];
#pragma unroll
    for (int r = 0; r < TILE_ROWS; ++r) { a0[r]=a1[r]=a2[r]=a3[r]=a4[r]=0.f; }
#pragma unroll
    for (int i = 0; i < NROWS_IN; ++i) {
        const float x = xv[i], y = yv[i];
        const float xx = x*x, yy = y*y, xy = x*y;
#pragma unroll
        for (int r = 0; r < TILE_ROWS; ++r) {
            const int t = i - r;
            if (t >= 0 && t <= 10) {
                const float w = GW[t];
                a0[r] = fmaf(w, x,  a0[r]);
                a1[r] = fmaf(w, y,  a1[r]);
                a2[r] = fmaf(w, xx, a2[r]);
                a3[r] = fmaf(w, yy, a3[r]);
                a4[r] = fmaf(w, xy, a4[r]);
            }
        }
    }
#pragma unroll
    for (int r = 0; r < TILE_ROWS; ++r) {
        vbuf[0][r][v] = a0[r];
        vbuf[1][r][v] = a1[r];
        vbuf[2][r][v] = a2[r];
        vbuf[3][r][v] = a3[r];
        vbuf[4][r][v] = a4[r];
    }
}

__global__ __launch_bounds__(NTHREADS)
void ssim_fused(const float* __restrict__ den, const float* __restrict__ cln,
                double* __restrict__ gacc) {
    __shared__ __align__(16) float vbuf[5][TILE_ROWS][VSTRIDE]; // 42,880 B
    __shared__ float red[NTHREADS/64];

    const int tid = threadIdx.x;
    const int b  = blockIdx.x;
    const int cs    = b & 1;          // 2 col strips
    const int rs    = (b >> 1) & 63;  // 64 row strips
    const int plane = b >> 7;         // 96 planes

    const int c0 = cs * TILE_COLS;
    const int y0 = rs * TILE_ROWS;
    const size_t pbase = (size_t)plane * (IMG_H * IMG_W);

    // ---- vertical stage: 266 cols over 256 threads (threads 0..9 do two) ----
    vertical_col(tid, c0, y0, pbase, den, cln, vbuf);
    if (tid < VCOLS - NTHREADS)
        vertical_col(NTHREADS + tid, c0, y0, pbase, den, cln, vbuf);
    __syncthreads();

    // ---- horizontal stage + SSIM: 512 items = exactly 2 per thread ----
    float ssim_acc = 0.f;
#pragma unroll
    for (int s = 0; s < 2; ++s) {
        const int item = tid + NTHREADS * s;
        const int row = item >> 6;          // 0..7
        const int j4  = (item & 63) << 2;   // 16B-aligned col in vbuf
        float bx[4], by[4], bxx[4], byy[4], bxy[4];
        hconv4(&vbuf[0][row][j4], bx);
        hconv4(&vbuf[1][row][j4], by);
        hconv4(&vbuf[2][row][j4], bxx);
        hconv4(&vbuf[3][row][j4], byy);
        hconv4(&vbuf[4][row][j4], bxy);
#pragma unroll
        for (int o = 0; o < 4; ++o) {
            const float C1 = 1e-4f, C2 = 9e-4f;
            const float mu1 = bx[o], mu2 = by[o];
            const float mu1s = mu1*mu1, mu2s = mu2*mu2, mu12 = mu1*mu2;
            const float s1  = bxx[o] - mu1s;
            const float s2  = byy[o] - mu2s;
            const float s12 = bxy[o] - mu12;
            const float num = (2.f*mu12 + C1) * (2.f*s12 + C2);
            const float dnm = (mu1s + mu2s + C1) * (s1 + s2 + C2);
            ssim_acc = fmaf(num, __builtin_amdgcn_rcpf(dnm), ssim_acc);
        }
    }

    // ---- block reduction, one f64 atomic per block ----
#pragma unroll
    for (int off = 32; off > 0; off >>= 1)
        ssim_acc += __shfl_down(ssim_acc, off, 64);
    if ((tid & 63) == 0) red[tid >> 6] = ssim_acc;
    __syncthreads();
    if (tid == 0) {
        float s = 0.f;
#pragma unroll
        for (int w = 0; w < NTHREADS/64; ++w) s += red[w];
        atomicAdd(gacc, (double)s);
    }
}

__global__ void ssim_finalize(const double* __restrict__ gacc, float* __restrict__ out,
                              double inv_n) {
    out[0] = 1.0f - (float)(gacc[0] * inv_n);
}

extern "C" void kernel_launch(void* const* d_in, const int* in_sizes, int n_in,
                              void* d_out, int out_size, void* d_ws, size_t ws_size,
                              hipStream_t stream) {
    const float* den = (const float*)d_in[0];
    const float* cln = (const float*)d_in[1];
    float* out = (float*)d_out;
    double* acc = (double*)d_ws;

    hipMemsetAsync(acc, 0, sizeof(double), stream);

    const int n = in_sizes[0];                 // 32*3*512*512
    const int planes = n / (IMG_H * IMG_W);    // 96
    dim3 grid(planes * 2 * 64);                // 2 col strips x 64 row strips
    ssim_fused<<<grid, NTHREADS, 0, stream>>>(den, cln, acc);
    ssim_finalize<<<1, 1, 0, stream>>>(acc, out, 1.0 / (double)n);
}

// Round 3
// 327.717 us; speedup vs baseline: 1.9829x; 1.3844x over previous
//
#include <hip/hip_runtime.h>

#define IMG_H 512
#define IMG_W 512
#define TILE_COLS 256               // output cols per block
#define TILE_ROWS 8                 // output rows per block
#define HALO 5
#define VCOLS (TILE_COLS + 2*HALO)  // 266 columns produced by vertical stage
#define NTHREADS 256                // 4 waves
#define VSTRIDE2 272                // halfs per row (8B-aligned groups of 4)
#define NROWS_IN (TILE_ROWS + 2*HALO)  // 18 input rows

typedef _Float16 h2 __attribute__((ext_vector_type(2)));

// Gaussian(sigma=1.5), 11 taps, normalized
#define W0 0.00102838f
#define W1 0.00759876f
#define W2 0.03600077f
#define W3 0.10936053f
#define W4 0.21300556f
#define W5 0.26601170f

static constexpr float GW[11] = { W0,W1,W2,W3,W4,W5,W4,W3,W2,W1,W0 };

// weight pairs for dot2: even outputs use [w0..w10,0], odd use [0,w0..w10]
static __device__ const h2 WEVEN[6] = {
    {(_Float16)W0,(_Float16)W1},{(_Float16)W2,(_Float16)W3},{(_Float16)W4,(_Float16)W5},
    {(_Float16)W4,(_Float16)W3},{(_Float16)W2,(_Float16)W1},{(_Float16)W0,(_Float16)0.f}
};
static __device__ const h2 WODD[6] = {
    {(_Float16)0.f,(_Float16)W0},{(_Float16)W1,(_Float16)W2},{(_Float16)W3,(_Float16)W4},
    {(_Float16)W5,(_Float16)W4},{(_Float16)W3,(_Float16)W2},{(_Float16)W1,(_Float16)W0}
};

// Horizontal 11-tap conv producing 4 consecutive outputs from 16 halfs at pp
// (pp is 8-byte aligned). f32 accumulation via v_dot2_f32_f16.
__device__ __forceinline__ void hconv4h(const _Float16* __restrict__ pp, float out[4]) {
    union { uint2 u2[4]; h2 p[8]; _Float16 h[16]; } w;
#pragma unroll
    for (int v = 0; v < 4; ++v) w.u2[v] = *(const uint2*)(pp + 4*v);
#if __has_builtin(__builtin_amdgcn_fdot2)
#pragma unroll
    for (int o = 0; o < 4; ++o) {
        const int base = o >> 1;
        float s = 0.f;
        if (o & 1) {
#pragma unroll
            for (int t = 0; t < 6; ++t)
                s = __builtin_amdgcn_fdot2(w.p[base + t], WODD[t], s, false);
        } else {
#pragma unroll
            for (int t = 0; t < 6; ++t)
                s = __builtin_amdgcn_fdot2(w.p[base + t], WEVEN[t], s, false);
        }
        out[o] = s;
    }
#else
    float f[16];
#pragma unroll
    for (int i = 0; i < 16; ++i) f[i] = (float)w.h[i];
#pragma unroll
    for (int o = 0; o < 4; ++o) {
        float s = 0.f;
#pragma unroll
        for (int t = 0; t < 11; ++t) s = fmaf(GW[t], f[o+t], s);
        out[o] = s;
    }
#endif
}

// Vertical 11-tap conv of {x,y,x^2,y^2,xy} for one column v, 8 output rows.
__device__ __forceinline__ void vertical_col(
    int v, int c0, int y0, size_t pbase,
    const float* __restrict__ den, const float* __restrict__ cln,
    _Float16 (*vbuf)[TILE_ROWS][VSTRIDE2]) {
    const int gc = c0 - HALO + v;
    const bool colok = (gc >= 0) && (gc < IMG_W);

    // all 36 loads issued before any use (128-VGPR budget via launch_bounds)
    float xv[NROWS_IN], yv[NROWS_IN];
#pragma unroll
    for (int i = 0; i < NROWS_IN; ++i) {
        const int gr = y0 - HALO + i;
        const bool ok = colok && ((unsigned)gr < (unsigned)IMG_H);
        float x = 0.f, y = 0.f;
        if (ok) {
            const size_t idx = pbase + (size_t)gr * IMG_W + gc;
            x = den[idx]; y = cln[idx];
        }
        xv[i] = x; yv[i] = y;
    }

    float a0[TILE_ROWS], a1[TILE_ROWS], a2[TILE_ROWS], a3[TILE_ROWS], a4[TILE_ROWS];
#pragma unroll
    for (int r = 0; r < TILE_ROWS; ++r) { a0[r]=a1[r]=a2[r]=a3[r]=a4[r]=0.f; }
#pragma unroll
    for (int i = 0; i < NROWS_IN; ++i) {
        const float x = fminf(fmaxf(xv[i], 0.f), 1.f);
        const float y = fminf(fmaxf(yv[i], 0.f), 1.f);
        const float xx = x*x, yy = y*y, xy = x*y;
#pragma unroll
        for (int r = 0; r < TILE_ROWS; ++r) {
            const int t = i - r;
            if (t >= 0 && t <= 10) {
                const float w = GW[t];
                a0[r] = fmaf(w, x,  a0[r]);
                a1[r] = fmaf(w, y,  a1[r]);
                a2[r] = fmaf(w, xx, a2[r]);
                a3[r] = fmaf(w, yy, a3[r]);
                a4[r] = fmaf(w, xy, a4[r]);
            }
        }
    }
#pragma unroll
    for (int r = 0; r < TILE_ROWS; ++r) {
        vbuf[0][r][v] = (_Float16)a0[r];
        vbuf[1][r][v] = (_Float16)a1[r];
        vbuf[2][r][v] = (_Float16)a2[r];
        vbuf[3][r][v] = (_Float16)a3[r];
        vbuf[4][r][v] = (_Float16)a4[r];
    }
}

__global__ __launch_bounds__(NTHREADS, 4)
void ssim_fused(const float* __restrict__ den, const float* __restrict__ cln,
                double* __restrict__ slots, int slotmask) {
    __shared__ __align__(16) _Float16 vbuf[5][TILE_ROWS][VSTRIDE2]; // 21,760 B
    __shared__ float red[NTHREADS/64];

    const int tid = threadIdx.x;
    const int b  = blockIdx.x;
    const int cs    = b & 1;          // 2 col strips
    const int rs    = (b >> 1) & 63;  // 64 row strips
    const int plane = b >> 7;         // 96 planes

    const int c0 = cs * TILE_COLS;
    const int y0 = rs * TILE_ROWS;
    const size_t pbase = (size_t)plane * (IMG_H * IMG_W);

    // ---- vertical stage: 266 cols over 256 threads (threads 0..9 do two) ----
    vertical_col(tid, c0, y0, pbase, den, cln, vbuf);
    if (tid < VCOLS - NTHREADS)
        vertical_col(NTHREADS + tid, c0, y0, pbase, den, cln, vbuf);
    __syncthreads();

    // ---- horizontal stage + SSIM: 512 items = exactly 2 per thread ----
    float ssim_acc = 0.f;
#pragma unroll
    for (int s = 0; s < 2; ++s) {
        const int item = tid + NTHREADS * s;
        const int row = item >> 6;          // 0..7
        const int j4  = (item & 63) << 2;   // start col in vbuf (8B-aligned halfs)
        float bx[4], by[4], bxx[4], byy[4], bxy[4];
        hconv4h(&vbuf[0][row][j4], bx);
        hconv4h(&vbuf[1][row][j4], by);
        hconv4h(&vbuf[2][row][j4], bxx);
        hconv4h(&vbuf[3][row][j4], byy);
        hconv4h(&vbuf[4][row][j4], bxy);
#pragma unroll
        for (int o = 0; o < 4; ++o) {
            const float C1 = 1e-4f, C2 = 9e-4f;
            const float mu1 = bx[o], mu2 = by[o];
            const float mu1s = mu1*mu1, mu2s = mu2*mu2, mu12 = mu1*mu2;
            const float s1  = bxx[o] - mu1s;
            const float s2  = byy[o] - mu2s;
            const float s12 = bxy[o] - mu12;
            const float num = (2.f*mu12 + C1) * (2.f*s12 + C2);
            const float dnm = (mu1s + mu2s + C1) * (s1 + s2 + C2);
            ssim_acc = fmaf(num, __builtin_amdgcn_rcpf(dnm), ssim_acc);
        }
    }

    // ---- block reduction, one f64 atomic per block into a hashed slot ----
#pragma unroll
    for (int off = 32; off > 0; off >>= 1)
        ssim_acc += __shfl_down(ssim_acc, off, 64);
    if ((tid & 63) == 0) red[tid >> 6] = ssim_acc;
    __syncthreads();
    if (tid == 0) {
        float s = 0.f;
#pragma unroll
        for (int w = 0; w < NTHREADS/64; ++w) s += red[w];
        // slot stride = 8 doubles (64 B) to avoid cacheline contention
        atomicAdd(&slots[(size_t)(b & slotmask) * 8], (double)s);
    }
}

__global__ void ssim_finalize(const double* __restrict__ slots, int nslots,
                              float* __restrict__ out, double inv_n) {
    double s = 0.0;
    for (int i = 0; i < nslots; ++i) s += slots[i * 8];
    out[0] = 1.0f - (float)(s * inv_n);
}

extern "C" void kernel_launch(void* const* d_in, const int* in_sizes, int n_in,
                              void* d_out, int out_size, void* d_ws, size_t ws_size,
                              hipStream_t stream) {
    const float* den = (const float*)d_in[0];
    const float* cln = (const float*)d_in[1];
    float* out = (float*)d_out;
    double* slots = (double*)d_ws;

    int nslots = 64;
    while (nslots > 1 && ws_size < (size_t)nslots * 64) nslots >>= 1;
    const size_t zbytes = (nslots == 1) ? sizeof(double) : (size_t)nslots * 64;
    hipMemsetAsync(slots, 0, zbytes, stream);

    const int n = in_sizes[0];                 // 32*3*512*512
    const int planes = n / (IMG_H * IMG_W);    // 96
    dim3 grid(planes * 2 * 64);                // 2 col strips x 64 row strips
    ssim_fused<<<grid, NTHREADS, 0, stream>>>(den, cln, slots, nslots - 1);
    ssim_finalize<<<1, 1, 0, stream>>>(slots, nslots, out, 1.0 / (double)n);
}